// Round 1
// baseline (1350.669 us; speedup 1.0000x reference)
//
#include <hip/hip_runtime.h>
#include <math.h>

namespace {

constexpr int N   = 20000;
constexpr int E   = 250000;
constexpr int B   = 8;
constexpr int D   = 32;
constexpr int R2  = 100;
constexpr int L   = 6;
constexpr int NEG = 32;
constexpr float EPSF = 1e-6f;

constexpr int BD = B * D;        // 256
constexpr int NPB = 8;           // nodes per block in layer kernel
constexpr int AROW = 162;        // padded A row (160 + 2) -> 2-way-free LDS banks
constexpr int CPAD = 34;         // padded C row for reduction

// ---------------- init ----------------
__global__ void k_init(float* x0, int* cnt, int* fill, float* meanacc) {
  int i = blockIdx.x * blockDim.x + threadIdx.x;
  int stride = gridDim.x * blockDim.x;
  for (int t = i; t < N * BD; t += stride) x0[t] = 0.f;
  for (int t = i; t < N; t += stride) { cnt[t] = 0; fill[t] = 0; }
  if (i == 0) meanacc[0] = 0.f;
}

// query gather + boundary scatter (x0 must be zeroed first)
__global__ void k_query(const int* __restrict__ r_index, const int* __restrict__ h_index,
                        const float* __restrict__ query_emb, float* query, float* x0) {
  int tid = threadIdx.x;            // 256
  int b = tid >> 5, d = tid & 31;
  float q = query_emb[r_index[b] * D + d];
  query[tid] = q;
  x0[h_index[b] * BD + tid] = q;    // boundary[h_index[b], b, d] = query[b,d]
}

__global__ void k_count(const int* __restrict__ edge_dst, int* cnt) {
  int e = blockIdx.x * blockDim.x + threadIdx.x;
  if (e < E) atomicAdd(&cnt[edge_dst[e]], 1);
}

// single-block exclusive scan over N counts -> row_start[N+1]
__global__ void k_scan(const int* __restrict__ cnt, int* row_start) {
  __shared__ int wsum[4];
  __shared__ int srun;
  int tid = threadIdx.x;            // 256
  int lane = tid & 63, wv = tid >> 6;
  if (tid == 0) srun = 0;
  __syncthreads();
  for (int base = 0; base < N; base += 256) {
    int i = base + tid;
    int v = (i < N) ? cnt[i] : 0;
    int x = v;
    for (int o = 1; o < 64; o <<= 1) {
      int y = __shfl_up(x, o, 64);
      if (lane >= o) x += y;
    }
    if (lane == 63) wsum[wv] = x;
    __syncthreads();
    int add = 0;
    for (int w = 0; w < wv; ++w) add += wsum[w];
    int excl = x - v + add;
    if (i < N) row_start[i] = srun + excl;
    int tot = wsum[0] + wsum[1] + wsum[2] + wsum[3];
    __syncthreads();
    if (tid == 0) srun += tot;
    __syncthreads();
  }
  if (tid == 0) row_start[N] = srun;   // == E
}

// scatter edges into CSR slots; pack src | (type<<16)
__global__ void k_scatter(const int* __restrict__ edge_src, const int* __restrict__ edge_dst,
                          const int* __restrict__ edge_type, const int* __restrict__ row_start,
                          int* fill, int* packed) {
  int e = blockIdx.x * blockDim.x + threadIdx.x;
  if (e < E) {
    int dn = edge_dst[e];
    int pos = atomicAdd(&fill[dn], 1);
    packed[row_start[dn] + pos] = edge_src[e] | (edge_type[e] << 16);
  }
}

__global__ void k_logsum(const int* __restrict__ cnt, float* meanacc) {
  int i = blockIdx.x * blockDim.x + threadIdx.x;
  float v = (i < N) ? logf((float)(cnt[i] + 1)) : 0.f;
  for (int o = 32; o > 0; o >>= 1) v += __shfl_down(v, o, 64);
  __shared__ float ws4[4];
  int lane = threadIdx.x & 63, wv = threadIdx.x >> 6;
  if (lane == 0) ws4[wv] = v;
  __syncthreads();
  if (threadIdx.x == 0) atomicAdd(meanacc, ws4[0] + ws4[1] + ws4[2] + ws4[3]);
}

__global__ void k_scales(const int* __restrict__ cnt, const float* __restrict__ meanacc,
                         float* scales) {
  int i = blockIdx.x * blockDim.x + threadIdx.x;
  if (i < N) {
    float m = meanacc[0] / (float)N;
    float s = logf((float)(cnt[i] + 1)) / m;
    scales[i * 3 + 0] = 1.f;
    scales[i * 3 + 1] = s;
    scales[i * 3 + 2] = 1.f / fmaxf(s, 0.01f);
  }
}

// rel[l][b][r][d] = br[l][r*D+d] + sum_k query[b][k] * Wr[l][r*D+d][k]
__global__ void k_rel(const float* __restrict__ query, const float* __restrict__ Wr,
                      const float* __restrict__ br, float* rel) {
  int o = blockIdx.x * blockDim.x + threadIdx.x;
  if (o >= L * B * R2 * D) return;
  int d = o & 31;
  int r = (o >> 5) % R2;
  int b = (o / (R2 * D)) % B;
  int l = o / (B * R2 * D);
  int rd = r * D + d;
  const float* wrow = Wr + ((size_t)l * R2 * D + rd) * D;
  const float* q = query + b * D;
  float acc = br[l * R2 * D + rd];
#pragma unroll
  for (int k = 0; k < D; ++k) acc = fmaf(q[k], wrow[k], acc);
  rel[o] = acc;
}

// k-major weight transpose per layer:
//  WT_l[k*32+dout]                    = Wl[l][dout][k]            (k<32, x part)
//  WT_l[1024 + ((s*128+f)*32)+dout]   = Wl[l][dout][32 + 3f + s]  (feat part)
__global__ void k_wt(const float* __restrict__ Wl, float* WT) {
  int o = blockIdx.x * blockDim.x + threadIdx.x;
  if (o >= L * 13312) return;
  int l = o / 13312, t = o % 13312;
  const float* wl = Wl + (size_t)l * D * 416;
  float v;
  if (t < 1024) {
    int k = t >> 5, dout = t & 31;
    v = wl[dout * 416 + k];
  } else {
    int u = t - 1024;
    int dout = u & 31;
    int sf = u >> 5;
    int s = sf >> 7, f = sf & 127;
    v = wl[dout * 416 + 32 + 3 * f + s];
  }
  WT[o] = v;
}

// -------------- fused layer kernel: 8 nodes / block, 256 threads --------------
__global__ __launch_bounds__(256) void k_layer(
    const float* __restrict__ xin, float* __restrict__ xout,
    const float* __restrict__ rel_l, const float* __restrict__ WT_l,
    const float* __restrict__ bl_l, const float* __restrict__ scales,
    const int* __restrict__ row_start, const int* __restrict__ packed,
    const int* __restrict__ h_index, const float* __restrict__ query) {
  __shared__ float Asm[64 * AROW];   // 41,472 B; reused as C (256*34 floats) later

  int tid = threadIdx.x;
  int b = tid >> 5, d = tid & 31;
  int node0 = blockIdx.x * NPB;

  int hb = h_index[b];
  float qv = query[tid];
  const float* relb = rel_l + b * (R2 * D) + d;

  // -------- aggregation --------
  for (int nn = 0; nn < NPB; ++nn) {
    int node = node0 + nn;
    int rs = row_start[node];
    int cntE = row_start[node + 1] - rs;
    float s1 = 0.f, s2 = 0.f;
    float mx = -INFINITY, mn = INFINITY;
    for (int j = 0; j < cntE; ++j) {
      int pk = packed[rs + j];        // block-uniform -> scalar load
      int se = pk & 0xFFFF;
      int et = pk >> 16;
      float xv = xin[se * BD + tid];  // coalesced row gather
      float rv = relb[et * D];
      float m = xv * rv;
      s1 += m;
      s2 = fmaf(m, m, s2);
      mx = fmaxf(mx, m);
      mn = fminf(mn, m);
    }
    float bnd = (hb == node) ? qv : 0.f;   // boundary self-message
    s1 += bnd;
    s2 = fmaf(bnd, bnd, s2);
    mx = fmaxf(mx, bnd);
    mn = fminf(mn, bnd);
    float invdeg = 1.f / (float)(cntE + 1);
    float mean = s1 * invdeg;
    float sqm = s2 * invdeg;
    float sd = sqrtf(fmaxf(sqm - mean * mean, EPSF));
    float xold = xin[node * BD + tid];

    float* arow = &Asm[(nn * 8 + b) * AROW];
    arow[d] = xold;
    float* af = &arow[32 + 4 * d];
    af[0] = mean; af[1] = mx; af[2] = mn; af[3] = sd;
  }
  __syncthreads();

  // -------- GEMM: out[nb][32], K partitioned across the 4 waves (104 k each) --------
  int lane = tid & 63;
  int wv = __builtin_amdgcn_readfirstlane(tid >> 6);
  const float* arow = &Asm[lane * AROW];
  int mynode = node0 + (lane >> 3);
  float sc1 = scales[mynode * 3 + 1];
  float sc2 = scales[mynode * 3 + 2];

  float out[32];
#pragma unroll
  for (int j = 0; j < 32; ++j) out[j] = 0.f;

  auto seg = [&](const float* wbase, const float* abase, int kb, int ke, float scale) {
    float acc[32];
#pragma unroll
    for (int j = 0; j < 32; ++j) acc[j] = 0.f;
    for (int k = kb; k < ke; k += 2) {
      float a0 = abase[k];
      float a1 = abase[k + 1];
      const float* w0 = wbase + k * 32;   // wave-uniform -> s_load + SGPR-operand FMA
      const float* w1 = w0 + 32;
#pragma unroll
      for (int j = 0; j < 32; ++j) acc[j] = fmaf(a0, w0[j], acc[j]);
#pragma unroll
      for (int j = 0; j < 32; ++j) acc[j] = fmaf(a1, w1[j], acc[j]);
    }
#pragma unroll
    for (int j = 0; j < 32; ++j) out[j] = fmaf(scale, acc[j], out[j]);
  };

  const float* WX = WT_l;          // x part  [k*32+dout], K=32
  const float* WF = WT_l + 1024;   // feat    [(s*128+f)*32+dout], K=128 per s
  if (wv == 0) {
    seg(WX, arow, 0, 32, 1.f);
    seg(WF + 0 * 4096, arow + 32, 0, 72, 1.f);
  } else if (wv == 1) {
    seg(WF + 0 * 4096, arow + 32, 72, 128, 1.f);
    seg(WF + 1 * 4096, arow + 32, 0, 48, sc1);
  } else if (wv == 2) {
    seg(WF + 1 * 4096, arow + 32, 48, 128, sc1);
    seg(WF + 2 * 4096, arow + 32, 0, 24, sc2);
  } else {
    seg(WF + 2 * 4096, arow + 32, 24, 128, sc2);
  }

  // -------- cross-wave reduce + bias + relu + store --------
  __syncthreads();                 // all A reads done; reuse LDS as C
  float* C = Asm;
  int crow = (wv * 64 + lane) * CPAD;
#pragma unroll
  for (int j = 0; j < 16; ++j)
    *(float2*)&C[crow + 2 * j] = make_float2(out[2 * j], out[2 * j + 1]);
  __syncthreads();
#pragma unroll
  for (int i = 0; i < 8; ++i) {
    int idx = tid + i * 256;
    int nb = idx >> 5, j = idx & 31;
    float v = C[nb * CPAD + j] + C[(64 + nb) * CPAD + j] +
              C[(128 + nb) * CPAD + j] + C[(192 + nb) * CPAD + j];
    v += bl_l[j];
    v = fmaxf(v, 0.f);
    xout[node0 * BD + idx] = v;    // coalesced
  }
}

// -------------- scoring head: one block per (b, neg) --------------
__global__ void k_score(const float* __restrict__ xL, const float* __restrict__ query,
                        const int* __restrict__ t_index, const float* __restrict__ W1,
                        const float* __restrict__ b1, const float* __restrict__ W2,
                        const float* __restrict__ b2, float* outp) {
  int bn = blockIdx.x;             // b*NEG + neg
  int b = bn >> 5;
  int j = threadIdx.x;             // 64
  __shared__ float f[64];
  int t = t_index[bn];
  f[j] = (j < 32) ? xL[t * BD + b * D + j] : query[b * D + (j - 32)];
  __syncthreads();
  const float* w1r = W1 + j * 64;
  float h = b1[j];
#pragma unroll
  for (int k = 0; k < 64; ++k) h = fmaf(f[k], w1r[k], h);
  h = fmaxf(h, 0.f);
  float p = h * W2[j];
#pragma unroll
  for (int o = 32; o > 0; o >>= 1) p += __shfl_down(p, o, 64);
  if (j == 0) outp[bn] = p + b2[0];
}

} // namespace

extern "C" void kernel_launch(void* const* d_in, const int* in_sizes, int n_in,
                              void* d_out, int out_size, void* d_ws, size_t ws_size,
                              hipStream_t stream) {
  const int* edge_src   = (const int*)d_in[0];
  const int* edge_dst   = (const int*)d_in[1];
  const int* edge_type  = (const int*)d_in[2];
  const int* h_index    = (const int*)d_in[3];
  const int* t_index    = (const int*)d_in[4];
  const int* r_index    = (const int*)d_in[5];
  const float* query_emb= (const float*)d_in[6];
  const float* Wr       = (const float*)d_in[7];
  const float* br       = (const float*)d_in[8];
  const float* Wl       = (const float*)d_in[9];
  const float* bl       = (const float*)d_in[10];
  const float* W1       = (const float*)d_in[11];
  const float* b1       = (const float*)d_in[12];
  const float* W2       = (const float*)d_in[13];
  const float* b2       = (const float*)d_in[14];
  float* outp = (float*)d_out;
  (void)in_sizes; (void)n_in; (void)out_size; (void)ws_size;

  char* w = (char*)d_ws;
  auto alloc = [&](size_t bytes) {
    char* p = w;
    w += (bytes + 511) & ~(size_t)511;
    return p;
  };
  float* x0      = (float*)alloc(sizeof(float) * N * BD);
  float* x1      = (float*)alloc(sizeof(float) * N * BD);
  float* rel     = (float*)alloc(sizeof(float) * L * B * R2 * D);
  float* WT      = (float*)alloc(sizeof(float) * L * 13312);
  float* query   = (float*)alloc(sizeof(float) * BD);
  float* scales  = (float*)alloc(sizeof(float) * N * 3);
  float* meanacc = (float*)alloc(sizeof(float) * 16);
  int* row_start = (int*)alloc(sizeof(int) * (N + 1));
  int* cnt       = (int*)alloc(sizeof(int) * N);
  int* fill      = (int*)alloc(sizeof(int) * N);
  int* packed    = (int*)alloc(sizeof(int) * E);

  k_init<<<2048, 256, 0, stream>>>(x0, cnt, fill, meanacc);
  k_query<<<1, 256, 0, stream>>>(r_index, h_index, query_emb, query, x0);
  k_count<<<(E + 255) / 256, 256, 0, stream>>>(edge_dst, cnt);
  k_scan<<<1, 256, 0, stream>>>(cnt, row_start);
  k_scatter<<<(E + 255) / 256, 256, 0, stream>>>(edge_src, edge_dst, edge_type,
                                                 row_start, fill, packed);
  k_logsum<<<(N + 255) / 256, 256, 0, stream>>>(cnt, meanacc);
  k_scales<<<(N + 255) / 256, 256, 0, stream>>>(cnt, meanacc, scales);
  k_rel<<<(L * B * R2 * D + 255) / 256, 256, 0, stream>>>(query, Wr, br, rel);
  k_wt<<<(L * 13312 + 255) / 256, 256, 0, stream>>>(Wl, WT);

  const float* xin = x0;
  float* xout = x1;
  for (int l = 0; l < L; ++l) {
    k_layer<<<N / NPB, 256, 0, stream>>>(xin, xout,
        rel + (size_t)l * B * R2 * D, WT + (size_t)l * 13312, bl + l * D,
        scales, row_start, packed, h_index, query);
    const float* t = xout;
    xout = (float*)xin;
    xin = t;
  }
  // L is even -> final activations are back in x0 (== xin after last swap)
  k_score<<<B * NEG, 64, 0, stream>>>(xin, query, t_index, W1, b1, W2, b2, outp);
}

// Round 2
// 817.659 us; speedup vs baseline: 1.6519x; 1.6519x over previous
//
#include <hip/hip_runtime.h>
#include <math.h>

namespace {

constexpr int N   = 20000;
constexpr int E   = 250000;
constexpr int B   = 8;
constexpr int D   = 32;
constexpr int R2  = 100;
constexpr int L   = 6;
constexpr int NEG = 32;
constexpr float EPSF = 1e-6f;

constexpr int BD = B * D;        // 256
constexpr int NPB = 8;           // nodes per block in layer kernel
constexpr int AROW = 161;        // odd stride -> 2-way (free) LDS bank aliasing
constexpr int CPAD = 33;         // odd stride for C reduction slabs

// ---------------- init ----------------
__global__ void k_init(float* x0, int* cnt, int* fill, float* meanacc) {
  int i = blockIdx.x * blockDim.x + threadIdx.x;
  int stride = gridDim.x * blockDim.x;
  for (int t = i; t < N * BD; t += stride) x0[t] = 0.f;
  for (int t = i; t < N; t += stride) { cnt[t] = 0; fill[t] = 0; }
  if (i == 0) meanacc[0] = 0.f;
}

// query gather + boundary scatter (x0 must be zeroed first)
__global__ void k_query(const int* __restrict__ r_index, const int* __restrict__ h_index,
                        const float* __restrict__ query_emb, float* query, float* x0) {
  int tid = threadIdx.x;            // 256
  int b = tid >> 5, d = tid & 31;
  float q = query_emb[r_index[b] * D + d];
  query[tid] = q;
  x0[h_index[b] * BD + tid] = q;    // boundary[h_index[b], b, d] = query[b,d]
}

__global__ void k_count(const int* __restrict__ edge_dst, int* cnt) {
  int e = blockIdx.x * blockDim.x + threadIdx.x;
  if (e < E) atomicAdd(&cnt[edge_dst[e]], 1);
}

// single-block exclusive scan over N counts -> row_start[N+1]
__global__ void k_scan(const int* __restrict__ cnt, int* row_start) {
  __shared__ int wsum[4];
  __shared__ int srun;
  int tid = threadIdx.x;            // 256
  int lane = tid & 63, wv = tid >> 6;
  if (tid == 0) srun = 0;
  __syncthreads();
  for (int base = 0; base < N; base += 256) {
    int i = base + tid;
    int v = (i < N) ? cnt[i] : 0;
    int x = v;
    for (int o = 1; o < 64; o <<= 1) {
      int y = __shfl_up(x, o, 64);
      if (lane >= o) x += y;
    }
    if (lane == 63) wsum[wv] = x;
    __syncthreads();
    int add = 0;
    for (int w = 0; w < wv; ++w) add += wsum[w];
    int excl = x - v + add;
    if (i < N) row_start[i] = srun + excl;
    int tot = wsum[0] + wsum[1] + wsum[2] + wsum[3];
    __syncthreads();
    if (tid == 0) srun += tot;
    __syncthreads();
  }
  if (tid == 0) row_start[N] = srun;   // == E
}

// scatter edges into CSR slots; pack src | (type<<16)
__global__ void k_scatter(const int* __restrict__ edge_src, const int* __restrict__ edge_dst,
                          const int* __restrict__ edge_type, const int* __restrict__ row_start,
                          int* fill, int* packed) {
  int e = blockIdx.x * blockDim.x + threadIdx.x;
  if (e < E) {
    int dn = edge_dst[e];
    int pos = atomicAdd(&fill[dn], 1);
    packed[row_start[dn] + pos] = edge_src[e] | (edge_type[e] << 16);
  }
}

__global__ void k_logsum(const int* __restrict__ cnt, float* meanacc) {
  int i = blockIdx.x * blockDim.x + threadIdx.x;
  float v = (i < N) ? logf((float)(cnt[i] + 1)) : 0.f;
  for (int o = 32; o > 0; o >>= 1) v += __shfl_down(v, o, 64);
  __shared__ float ws4[4];
  int lane = threadIdx.x & 63, wv = threadIdx.x >> 6;
  if (lane == 0) ws4[wv] = v;
  __syncthreads();
  if (threadIdx.x == 0) atomicAdd(meanacc, ws4[0] + ws4[1] + ws4[2] + ws4[3]);
}

__global__ void k_scales(const int* __restrict__ cnt, const float* __restrict__ meanacc,
                         float* scales) {
  int i = blockIdx.x * blockDim.x + threadIdx.x;
  if (i < N) {
    float m = meanacc[0] / (float)N;
    float s = logf((float)(cnt[i] + 1)) / m;
    scales[i * 3 + 0] = 1.f;
    scales[i * 3 + 1] = s;
    scales[i * 3 + 2] = 1.f / fmaxf(s, 0.01f);
  }
}

// rel[l][b][r][d] = br[l][r*D+d] + sum_k query[b][k] * Wr[l][r*D+d][k]
__global__ void k_rel(const float* __restrict__ query, const float* __restrict__ Wr,
                      const float* __restrict__ br, float* rel) {
  int o = blockIdx.x * blockDim.x + threadIdx.x;
  if (o >= L * B * R2 * D) return;
  int d = o & 31;
  int r = (o >> 5) % R2;
  int b = (o / (R2 * D)) % B;
  int l = o / (B * R2 * D);
  int rd = r * D + d;
  const float* wrow = Wr + ((size_t)l * R2 * D + rd) * D;
  const float* q = query + b * D;
  float acc = br[l * R2 * D + rd];
#pragma unroll
  for (int k = 0; k < D; ++k) acc = fmaf(q[k], wrow[k], acc);
  rel[o] = acc;
}

// k-major weight transpose per layer:
//  WT_l[k*32+dout]                    = Wl[l][dout][k]            (k<32, x part)
//  WT_l[1024 + ((s*128+f)*32)+dout]   = Wl[l][dout][32 + 3f + s]  (feat part)
__global__ void k_wt(const float* __restrict__ Wl, float* WT) {
  int o = blockIdx.x * blockDim.x + threadIdx.x;
  if (o >= L * 13312) return;
  int l = o / 13312, t = o % 13312;
  const float* wl = Wl + (size_t)l * D * 416;
  float v;
  if (t < 1024) {
    int k = t >> 5, dout = t & 31;
    v = wl[dout * 416 + k];
  } else {
    int u = t - 1024;
    int dout = u & 31;
    int sf = u >> 5;
    int s = sf >> 7, f = sf & 127;
    v = wl[dout * 416 + 32 + 3 * f + s];
  }
  WT[o] = v;
}

// ---- fused layer kernel: 8 nodes / block, 512 threads (8 waves) ----
// Aggregation: thread-halves process 4 nodes each (doubles gather MLP).
// GEMM: lane = output row (64 rows), 8 waves split virtual-K=416 into 52 each.
// 3 blocks/CU via 41.2 KB LDS -> 24 waves/CU (75% occupancy target).
__global__ __launch_bounds__(512, 6) void k_layer(
    const float* __restrict__ xin, float* __restrict__ xout,
    const float* __restrict__ rel_l, const float* __restrict__ WT_l,
    const float* __restrict__ bl_l, const float* __restrict__ scales,
    const int* __restrict__ row_start, const int* __restrict__ packed,
    const int* __restrict__ h_index, const float* __restrict__ query) {
  __shared__ float Asm[64 * AROW];   // 41,216 B; reused as C slabs later

  int tid = threadIdx.x;
  int ch = tid & 255;
  int b = ch >> 5, d = ch & 31;
  int half = __builtin_amdgcn_readfirstlane(tid >> 8);  // wave-uniform 0/1
  int node0 = blockIdx.x * NPB;

  int hb = h_index[b];
  float qv = query[ch];
  const float* relb = rel_l + b * (R2 * D) + d;

  // -------- aggregation: this half handles nodes node0 + half*4 + [0,4) --------
  for (int nn = 0; nn < 4; ++nn) {
    int node = node0 + half * 4 + nn;
    int rs = row_start[node];
    int cntE = row_start[node + 1] - rs;
    float s1 = 0.f, s2 = 0.f;
    float mx = -INFINITY, mn = INFINITY;
    int j = 0;
    for (; j + 1 < cntE; j += 2) {       // 2 gathers in flight
      int pk0 = packed[rs + j];          // wave-uniform -> scalar loads
      int pk1 = packed[rs + j + 1];
      float xv0 = xin[(pk0 & 0xFFFF) * BD + ch];
      float xv1 = xin[(pk1 & 0xFFFF) * BD + ch];
      float rv0 = relb[(pk0 >> 16) * D];
      float rv1 = relb[(pk1 >> 16) * D];
      float m0 = xv0 * rv0;
      float m1 = xv1 * rv1;
      s1 += m0; s2 = fmaf(m0, m0, s2);
      mx = fmaxf(mx, m0); mn = fminf(mn, m0);
      s1 += m1; s2 = fmaf(m1, m1, s2);
      mx = fmaxf(mx, m1); mn = fminf(mn, m1);
    }
    if (j < cntE) {
      int pk = packed[rs + j];
      float xv = xin[(pk & 0xFFFF) * BD + ch];
      float rv = relb[(pk >> 16) * D];
      float m = xv * rv;
      s1 += m; s2 = fmaf(m, m, s2);
      mx = fmaxf(mx, m); mn = fminf(mn, m);
    }
    float bnd = (hb == node) ? qv : 0.f;   // boundary self-message
    s1 += bnd;
    s2 = fmaf(bnd, bnd, s2);
    mx = fmaxf(mx, bnd);
    mn = fminf(mn, bnd);
    float invdeg = 1.f / (float)(cntE + 1);
    float mean = s1 * invdeg;
    float sqm = s2 * invdeg;
    float sd = sqrtf(fmaxf(sqm - mean * mean, EPSF));
    float xold = xin[node * BD + ch];

    int r = (half * 4 + nn) * 8 + b;
    float* arow = &Asm[r * AROW];
    arow[d] = xold;
    float* af = &arow[32 + 4 * d];
    af[0] = mean; af[1] = mx; af[2] = mn; af[3] = sd;
  }
  __syncthreads();

  // -------- GEMM: out[row=lane][32], virtual K=416 split 8 ways (52/wave) --------
  int lane = tid & 63;
  int wv = __builtin_amdgcn_readfirstlane(tid >> 6);   // 0..7
  const float* arow = &Asm[lane * AROW];
  int mynode = node0 + (lane >> 3);
  float sc1 = scales[mynode * 3 + 1];
  float sc2 = scales[mynode * 3 + 2];

  float out[32];
#pragma unroll
  for (int j = 0; j < 32; ++j) out[j] = 0.f;

  auto seg = [&](const float* wbase, const float* abase, int k0, int k1, float scale) {
    float acc[32];
#pragma unroll
    for (int j = 0; j < 32; ++j) acc[j] = 0.f;
    for (int k = k0; k < k1; ++k) {
      float a0 = abase[k];
      const float* w0 = wbase + k * 32;   // wave-uniform -> s_load + SGPR-operand FMA
#pragma unroll
      for (int j = 0; j < 32; ++j) acc[j] = fmaf(a0, w0[j], acc[j]);
    }
#pragma unroll
    for (int j = 0; j < 32; ++j) out[j] = fmaf(scale, acc[j], out[j]);
  };

  // virtual-k axis: [0,32) = x-part (WX); [32+s*128, 32+(s+1)*128) = feat seg s
  const float* WX = WT_l;
  const float* WF = WT_l + 1024;
  int kb = wv * 52, ke = kb + 52;
  {
    int lo = kb < 0 ? 0 : kb, hi = ke < 32 ? ke : 32;
    if (lo < hi) seg(WX, arow, lo, hi, 1.f);
  }
#pragma unroll
  for (int s = 0; s < 3; ++s) {
    int vb = 32 + s * 128;
    int lo = kb > vb ? kb : vb;
    int hi = ke < vb + 128 ? ke : vb + 128;
    if (lo < hi) {
      float sc = (s == 0) ? 1.f : (s == 1 ? sc1 : sc2);
      seg(WF + s * 4096, arow + 32, lo - vb, hi - vb, sc);
    }
  }

  // -------- 2-round cross-wave reduction in LDS (reuse Asm) --------
  __syncthreads();                 // all A reads done
  float* C = Asm;
  if (wv >= 4) {                   // round 1: waves 4-7 write slabs 0-3
    float* c = &C[((wv - 4) * 64 + lane) * CPAD];
#pragma unroll
    for (int j = 0; j < 32; ++j) c[j] = out[j];
  }
  __syncthreads();
  if (wv < 4) {                    // waves 0-3 absorb
    const float* c = &C[(wv * 64 + lane) * CPAD];
#pragma unroll
    for (int j = 0; j < 32; ++j) out[j] += c[j];
  }
  __syncthreads();
  if (wv >= 1 && wv < 4) {         // round 2: waves 1-3 write slabs 0-2
    float* c = &C[((wv - 1) * 64 + lane) * CPAD];
#pragma unroll
    for (int j = 0; j < 32; ++j) c[j] = out[j];
  }
  __syncthreads();
  if (wv == 0) {                   // wave 0: final sum + bias + relu + store
    const float* c0 = &C[(0 * 64 + lane) * CPAD];
    const float* c1 = &C[(1 * 64 + lane) * CPAD];
    const float* c2 = &C[(2 * 64 + lane) * CPAD];
    float* dst = xout + (size_t)node0 * BD + lane * 32;
#pragma unroll
    for (int j = 0; j < 32; ++j) {
      float v = out[j] + c0[j] + c1[j] + c2[j] + bl_l[j];
      dst[j] = fmaxf(v, 0.f);
    }
  }
}

// -------------- scoring head: one block per (b, neg) --------------
__global__ void k_score(const float* __restrict__ xL, const float* __restrict__ query,
                        const int* __restrict__ t_index, const float* __restrict__ W1,
                        const float* __restrict__ b1, const float* __restrict__ W2,
                        const float* __restrict__ b2, float* outp) {
  int bn = blockIdx.x;             // b*NEG + neg
  int b = bn >> 5;
  int j = threadIdx.x;             // 64
  __shared__ float f[64];
  int t = t_index[bn];
  f[j] = (j < 32) ? xL[t * BD + b * D + j] : query[b * D + (j - 32)];
  __syncthreads();
  const float* w1r = W1 + j * 64;
  float h = b1[j];
#pragma unroll
  for (int k = 0; k < 64; ++k) h = fmaf(f[k], w1r[k], h);
  h = fmaxf(h, 0.f);
  float p = h * W2[j];
#pragma unroll
  for (int o = 32; o > 0; o >>= 1) p += __shfl_down(p, o, 64);
  if (j == 0) outp[bn] = p + b2[0];
}

} // namespace

extern "C" void kernel_launch(void* const* d_in, const int* in_sizes, int n_in,
                              void* d_out, int out_size, void* d_ws, size_t ws_size,
                              hipStream_t stream) {
  const int* edge_src   = (const int*)d_in[0];
  const int* edge_dst   = (const int*)d_in[1];
  const int* edge_type  = (const int*)d_in[2];
  const int* h_index    = (const int*)d_in[3];
  const int* t_index    = (const int*)d_in[4];
  const int* r_index    = (const int*)d_in[5];
  const float* query_emb= (const float*)d_in[6];
  const float* Wr       = (const float*)d_in[7];
  const float* br       = (const float*)d_in[8];
  const float* Wl       = (const float*)d_in[9];
  const float* bl       = (const float*)d_in[10];
  const float* W1       = (const float*)d_in[11];
  const float* b1       = (const float*)d_in[12];
  const float* W2       = (const float*)d_in[13];
  const float* b2       = (const float*)d_in[14];
  float* outp = (float*)d_out;
  (void)in_sizes; (void)n_in; (void)out_size; (void)ws_size;

  char* w = (char*)d_ws;
  auto alloc = [&](size_t bytes) {
    char* p = w;
    w += (bytes + 511) & ~(size_t)511;
    return p;
  };
  float* x0      = (float*)alloc(sizeof(float) * N * BD);
  float* x1      = (float*)alloc(sizeof(float) * N * BD);
  float* rel     = (float*)alloc(sizeof(float) * L * B * R2 * D);
  float* WT      = (float*)alloc(sizeof(float) * L * 13312);
  float* query   = (float*)alloc(sizeof(float) * BD);
  float* scales  = (float*)alloc(sizeof(float) * N * 3);
  float* meanacc = (float*)alloc(sizeof(float) * 16);
  int* row_start = (int*)alloc(sizeof(int) * (N + 1));
  int* cnt       = (int*)alloc(sizeof(int) * N);
  int* fill      = (int*)alloc(sizeof(int) * N);
  int* packed    = (int*)alloc(sizeof(int) * E);

  k_init<<<2048, 256, 0, stream>>>(x0, cnt, fill, meanacc);
  k_query<<<1, 256, 0, stream>>>(r_index, h_index, query_emb, query, x0);
  k_count<<<(E + 255) / 256, 256, 0, stream>>>(edge_dst, cnt);
  k_scan<<<1, 256, 0, stream>>>(cnt, row_start);
  k_scatter<<<(E + 255) / 256, 256, 0, stream>>>(edge_src, edge_dst, edge_type,
                                                 row_start, fill, packed);
  k_logsum<<<(N + 255) / 256, 256, 0, stream>>>(cnt, meanacc);
  k_scales<<<(N + 255) / 256, 256, 0, stream>>>(cnt, meanacc, scales);
  k_rel<<<(L * B * R2 * D + 255) / 256, 256, 0, stream>>>(query, Wr, br, rel);
  k_wt<<<(L * 13312 + 255) / 256, 256, 0, stream>>>(Wl, WT);

  const float* xin = x0;
  float* xout = x1;
  for (int l = 0; l < L; ++l) {
    k_layer<<<N / NPB, 512, 0, stream>>>(xin, xout,
        rel + (size_t)l * B * R2 * D, WT + (size_t)l * 13312, bl + l * D,
        scales, row_start, packed, h_index, query);
    const float* t = xout;
    xout = (float*)xin;
    xin = t;
  }
  // L is even -> final activations are back in x0 (== xin after last swap)
  k_score<<<B * NEG, 64, 0, stream>>>(xin, query, t_index, W1, b1, W2, b2, outp);
}

// Round 3
// 646.495 us; speedup vs baseline: 2.0892x; 1.2648x over previous
//
#include <hip/hip_runtime.h>
#include <math.h>

namespace {

constexpr int N   = 20000;
constexpr int E   = 250000;
constexpr int B   = 8;
constexpr int D   = 32;
constexpr int R2  = 100;
constexpr int L   = 6;
constexpr int NEG = 32;
constexpr float EPSF = 1e-6f;

constexpr int BD = B * D;        // 256
constexpr int NPB = 8;           // nodes per block in layer kernel
constexpr int CPAD = 33;         // odd stride for C reduction slabs
// LDS: max(feat panel 128*64, C slabs 4*64*33) floats
constexpr int LDSF = 4 * 64 * CPAD;   // 8448 floats = 33,792 B -> 4 blocks/CU

// ---------------- init ----------------
__global__ void k_init(float* x0, int* cnt, int* fill, float* meanacc) {
  int i = blockIdx.x * blockDim.x + threadIdx.x;
  int stride = gridDim.x * blockDim.x;
  for (int t = i; t < N * BD; t += stride) x0[t] = 0.f;
  for (int t = i; t < N; t += stride) { cnt[t] = 0; fill[t] = 0; }
  if (i == 0) meanacc[0] = 0.f;
}

// query gather + boundary scatter (x0 must be zeroed first)
__global__ void k_query(const int* __restrict__ r_index, const int* __restrict__ h_index,
                        const float* __restrict__ query_emb, float* query, float* x0) {
  int tid = threadIdx.x;            // 256
  int b = tid >> 5, d = tid & 31;
  float q = query_emb[r_index[b] * D + d];
  query[tid] = q;
  x0[h_index[b] * BD + tid] = q;    // boundary[h_index[b], b, d] = query[b,d]
}

__global__ void k_count(const int* __restrict__ edge_dst, int* cnt) {
  int e = blockIdx.x * blockDim.x + threadIdx.x;
  if (e < E) atomicAdd(&cnt[edge_dst[e]], 1);
}

// single-block exclusive scan over N counts -> row_start[N+1]
__global__ void k_scan(const int* __restrict__ cnt, int* row_start) {
  __shared__ int wsum[4];
  __shared__ int srun;
  int tid = threadIdx.x;            // 256
  int lane = tid & 63, wv = tid >> 6;
  if (tid == 0) srun = 0;
  __syncthreads();
  for (int base = 0; base < N; base += 256) {
    int i = base + tid;
    int v = (i < N) ? cnt[i] : 0;
    int x = v;
    for (int o = 1; o < 64; o <<= 1) {
      int y = __shfl_up(x, o, 64);
      if (lane >= o) x += y;
    }
    if (lane == 63) wsum[wv] = x;
    __syncthreads();
    int add = 0;
    for (int w = 0; w < wv; ++w) add += wsum[w];
    int excl = x - v + add;
    if (i < N) row_start[i] = srun + excl;
    int tot = wsum[0] + wsum[1] + wsum[2] + wsum[3];
    __syncthreads();
    if (tid == 0) srun += tot;
    __syncthreads();
  }
  if (tid == 0) row_start[N] = srun;   // == E
}

// scatter edges into CSR slots; pack src | (type<<16)
__global__ void k_scatter(const int* __restrict__ edge_src, const int* __restrict__ edge_dst,
                          const int* __restrict__ edge_type, const int* __restrict__ row_start,
                          int* fill, int* packed) {
  int e = blockIdx.x * blockDim.x + threadIdx.x;
  if (e < E) {
    int dn = edge_dst[e];
    int pos = atomicAdd(&fill[dn], 1);
    packed[row_start[dn] + pos] = edge_src[e] | (edge_type[e] << 16);
  }
}

__global__ void k_logsum(const int* __restrict__ cnt, float* meanacc) {
  int i = blockIdx.x * blockDim.x + threadIdx.x;
  float v = (i < N) ? logf((float)(cnt[i] + 1)) : 0.f;
  for (int o = 32; o > 0; o >>= 1) v += __shfl_down(v, o, 64);
  __shared__ float ws4[4];
  int lane = threadIdx.x & 63, wv = threadIdx.x >> 6;
  if (lane == 0) ws4[wv] = v;
  __syncthreads();
  if (threadIdx.x == 0) atomicAdd(meanacc, ws4[0] + ws4[1] + ws4[2] + ws4[3]);
}

__global__ void k_scales(const int* __restrict__ cnt, const float* __restrict__ meanacc,
                         float* scales) {
  int i = blockIdx.x * blockDim.x + threadIdx.x;
  if (i < N) {
    float m = meanacc[0] / (float)N;
    float s = logf((float)(cnt[i] + 1)) / m;
    scales[i * 3 + 0] = 1.f;
    scales[i * 3 + 1] = s;
    scales[i * 3 + 2] = 1.f / fmaxf(s, 0.01f);
  }
}

// rel[l][b][r][d] = br[l][r*D+d] + sum_k query[b][k] * Wr[l][r*D+d][k]
__global__ void k_rel(const float* __restrict__ query, const float* __restrict__ Wr,
                      const float* __restrict__ br, float* rel) {
  int o = blockIdx.x * blockDim.x + threadIdx.x;
  if (o >= L * B * R2 * D) return;
  int d = o & 31;
  int r = (o >> 5) % R2;
  int b = (o / (R2 * D)) % B;
  int l = o / (B * R2 * D);
  int rd = r * D + d;
  const float4* wrow = (const float4*)(Wr + ((size_t)l * R2 * D + rd) * D);
  const float* q = query + b * D;
  float acc = br[l * R2 * D + rd];
#pragma unroll
  for (int k = 0; k < 8; ++k) {
    float4 w4 = wrow[k];
    acc = fmaf(q[4 * k + 0], w4.x, acc);
    acc = fmaf(q[4 * k + 1], w4.y, acc);
    acc = fmaf(q[4 * k + 2], w4.z, acc);
    acc = fmaf(q[4 * k + 3], w4.w, acc);
  }
  rel[o] = acc;
}

// k-major weight transpose per layer:
//  WT_l[k*32+dout]                    = Wl[l][dout][k]            (k<32, x part)
//  WT_l[1024 + ((s*128+f)*32)+dout]   = Wl[l][dout][32 + 3f + s]  (feat part)
__global__ void k_wt(const float* __restrict__ Wl, float* WT) {
  int o = blockIdx.x * blockDim.x + threadIdx.x;
  if (o >= L * 13312) return;
  int l = o / 13312, t = o % 13312;
  const float* wl = Wl + (size_t)l * D * 416;
  float v;
  if (t < 1024) {
    int k = t >> 5, dout = t & 31;
    v = wl[dout * 416 + k];
  } else {
    int u = t - 1024;
    int dout = u & 31;
    int sf = u >> 5;
    int s = sf >> 7, f = sf & 127;
    v = wl[dout * 416 + 32 + 3 * f + s];
  }
  WT[o] = v;
}

// ---- fused layer kernel: 8 nodes / block, 512 threads (8 waves) ----
// Aggregation: thread-halves process 4 nodes each; stats written k-major
// swizzled to a feat-only LDS panel [128][64] (conflict-free both sides).
// GEMM: lane = output row (64 rows), 8 waves split virtual-K=416 into 52 each;
// x-part (K=32) read from global (own row, L1/L2-hot), scale folded into A.
// 33.8 KB LDS + <=64 VGPR -> 4 blocks/CU = 32 waves (100% occupancy target).
__global__ __launch_bounds__(512, 8) void k_layer(
    const float* __restrict__ xin, float* __restrict__ xout,
    const float* __restrict__ rel_l, const float* __restrict__ WT_l,
    const float* __restrict__ bl_l, const float* __restrict__ scales,
    const int* __restrict__ row_start, const int* __restrict__ packed,
    const int* __restrict__ h_index, const float* __restrict__ query) {
  __shared__ float Asm[LDSF];   // 33,792 B

  int tid = threadIdx.x;
  int ch = tid & 255;
  int b = ch >> 5, d = ch & 31;
  int half = __builtin_amdgcn_readfirstlane(tid >> 8);  // wave-uniform 0/1
  int node0 = blockIdx.x * NPB;

  int hb = h_index[b];
  float qv = query[ch];
  const float* relb = rel_l + b * (R2 * D) + d;

  // -------- aggregation: this half handles nodes node0 + half*4 + [0,4) --------
  for (int nn = 0; nn < 4; ++nn) {
    int node = node0 + half * 4 + nn;
    int rs = row_start[node];
    int cntE = row_start[node + 1] - rs;
    float s1 = 0.f, s2 = 0.f;
    float mx = -INFINITY, mn = INFINITY;
    int j = 0;
    for (; j + 3 < cntE; j += 4) {       // 4 gathers in flight
      int pk0 = packed[rs + j];          // wave-uniform -> scalar loads
      int pk1 = packed[rs + j + 1];
      int pk2 = packed[rs + j + 2];
      int pk3 = packed[rs + j + 3];
      float xv0 = xin[(pk0 & 0xFFFF) * BD + ch];
      float xv1 = xin[(pk1 & 0xFFFF) * BD + ch];
      float xv2 = xin[(pk2 & 0xFFFF) * BD + ch];
      float xv3 = xin[(pk3 & 0xFFFF) * BD + ch];
      float rv0 = relb[(pk0 >> 16) * D];
      float rv1 = relb[(pk1 >> 16) * D];
      float rv2 = relb[(pk2 >> 16) * D];
      float rv3 = relb[(pk3 >> 16) * D];
      float m0 = xv0 * rv0, m1 = xv1 * rv1, m2 = xv2 * rv2, m3 = xv3 * rv3;
      s1 += m0; s2 = fmaf(m0, m0, s2); mx = fmaxf(mx, m0); mn = fminf(mn, m0);
      s1 += m1; s2 = fmaf(m1, m1, s2); mx = fmaxf(mx, m1); mn = fminf(mn, m1);
      s1 += m2; s2 = fmaf(m2, m2, s2); mx = fmaxf(mx, m2); mn = fminf(mn, m2);
      s1 += m3; s2 = fmaf(m3, m3, s2); mx = fmaxf(mx, m3); mn = fminf(mn, m3);
    }
    for (; j < cntE; ++j) {
      int pk = packed[rs + j];
      float xv = xin[(pk & 0xFFFF) * BD + ch];
      float rv = relb[(pk >> 16) * D];
      float m = xv * rv;
      s1 += m; s2 = fmaf(m, m, s2);
      mx = fmaxf(mx, m); mn = fminf(mn, m);
    }
    float bnd = (hb == node) ? qv : 0.f;   // boundary self-message
    s1 += bnd;
    s2 = fmaf(bnd, bnd, s2);
    mx = fmaxf(mx, bnd);
    mn = fminf(mn, bnd);
    float invdeg = 1.f / (float)(cntE + 1);
    float mean = s1 * invdeg;
    float sqm = s2 * invdeg;
    float sd = sqrtf(fmaxf(sqm - mean * mean, EPSF));

    int r = (half * 4 + nn) * 8 + b;
    // k-major swizzled stat writes: f = 4d+st at Asm[f*64 + (r ^ ((f+(f>>2))&31))]
    float st4[4] = {mean, mx, mn, sd};
#pragma unroll
    for (int st = 0; st < 4; ++st) {
      int f = 4 * d + st;
      int S = (f + (f >> 2)) & 31;       // = (5d+st)&31 -> conflict-free
      Asm[f * 64 + (r ^ S)] = st4[st];
    }
  }
  __syncthreads();

  // -------- GEMM: out[row=lane][32], virtual K=416 split 8 ways (52/wave) --------
  int lane = tid & 63;
  int wv = __builtin_amdgcn_readfirstlane(tid >> 6);   // 0..7
  int mynode = node0 + (lane >> 3);
  float sc1 = scales[mynode * 3 + 1];
  float sc2 = scales[mynode * 3 + 2];

  float out[32];
#pragma unroll
  for (int j = 0; j < 32; ++j) out[j] = 0.f;

  int kb = wv * 52, ke = kb + 52;

  // x-part (virtual k in [0,32)): only wave 0; own row straight from global
  if (kb < 32) {
    const float* xrow = xin + (size_t)mynode * BD + (lane & 7) * 32;
    const float* WX = WT_l;
#pragma unroll
    for (int k = 0; k < 32; k += 4) {
      float4 xv = *(const float4*)&xrow[k];
      const float* w = WX + k * 32;
#pragma unroll
      for (int j = 0; j < 32; ++j) out[j] = fmaf(xv.x, w[j], out[j]);
#pragma unroll
      for (int j = 0; j < 32; ++j) out[j] = fmaf(xv.y, w[32 + j], out[j]);
#pragma unroll
      for (int j = 0; j < 32; ++j) out[j] = fmaf(xv.z, w[64 + j], out[j]);
#pragma unroll
      for (int j = 0; j < 32; ++j) out[j] = fmaf(xv.w, w[96 + j], out[j]);
    }
  }

  // feat segs (scale folded into A, matching reference (feat*scale)@W order)
  const float* WF = WT_l + 1024;
#pragma unroll
  for (int s = 0; s < 3; ++s) {
    int vb = 32 + s * 128;
    int lo = kb > vb ? kb : vb;
    int hi = ke < vb + 128 ? ke : vb + 128;
    if (lo < hi) {                       // (hi-lo) is always even
      float sc = (s == 0) ? 1.f : (s == 1 ? sc1 : sc2);
      const float* wseg = WF + s * 4096;
      for (int f = lo - vb; f < hi - vb; f += 2) {
        int f0 = f, f1 = f + 1;
        int S0 = (f0 + (f0 >> 2)) & 31;
        int S1 = (f1 + (f1 >> 2)) & 31;
        float a0 = Asm[f0 * 64 + (lane ^ S0)];
        float a1 = Asm[f1 * 64 + (lane ^ S1)];
        float as0 = a0 * sc, as1 = a1 * sc;
        const float* w0 = wseg + f0 * 32;
#pragma unroll
        for (int j = 0; j < 32; ++j) out[j] = fmaf(as0, w0[j], out[j]);
#pragma unroll
        for (int j = 0; j < 32; ++j) out[j] = fmaf(as1, w0[32 + j], out[j]);
      }
    }
  }

  // -------- 2-round cross-wave reduction in LDS (reuse Asm) --------
  __syncthreads();                 // all A reads done
  float* C = Asm;
  if (wv >= 4) {                   // round 1: waves 4-7 write slabs 0-3
    float* c = &C[((wv - 4) * 64 + lane) * CPAD];
#pragma unroll
    for (int j = 0; j < 32; ++j) c[j] = out[j];
  }
  __syncthreads();
  if (wv < 4) {                    // waves 0-3 absorb
    const float* c = &C[(wv * 64 + lane) * CPAD];
#pragma unroll
    for (int j = 0; j < 32; ++j) out[j] += c[j];
  }
  __syncthreads();
  if (wv >= 1 && wv < 4) {         // round 2: waves 1-3 write slabs 0-2
    float* c = &C[((wv - 1) * 64 + lane) * CPAD];
#pragma unroll
    for (int j = 0; j < 32; ++j) c[j] = out[j];
  }
  __syncthreads();
  if (wv == 0) {                   // wave 0: final sum + bias + relu + store
    const float* c0 = &C[(0 * 64 + lane) * CPAD];
    const float* c1 = &C[(1 * 64 + lane) * CPAD];
    const float* c2 = &C[(2 * 64 + lane) * CPAD];
    float* dst = xout + (size_t)node0 * BD + lane * 32;
#pragma unroll
    for (int j = 0; j < 32; ++j) {
      float v = out[j] + c0[j] + c1[j] + c2[j] + bl_l[j];
      dst[j] = fmaxf(v, 0.f);
    }
  }
}

// -------------- scoring head: one block per (b, neg) --------------
__global__ void k_score(const float* __restrict__ xL, const float* __restrict__ query,
                        const int* __restrict__ t_index, const float* __restrict__ W1,
                        const float* __restrict__ b1, const float* __restrict__ W2,
                        const float* __restrict__ b2, float* outp) {
  int bn = blockIdx.x;             // b*NEG + neg
  int b = bn >> 5;
  int j = threadIdx.x;             // 64
  __shared__ float f[64];
  int t = t_index[bn];
  f[j] = (j < 32) ? xL[t * BD + b * D + j] : query[b * D + (j - 32)];
  __syncthreads();
  const float* w1r = W1 + j * 64;
  float h = b1[j];
#pragma unroll
  for (int k = 0; k < 64; ++k) h = fmaf(f[k], w1r[k], h);
  h = fmaxf(h, 0.f);
  float p = h * W2[j];
#pragma unroll
  for (int o = 32; o > 0; o >>= 1) p += __shfl_down(p, o, 64);
  if (j == 0) outp[bn] = p + b2[0];
}

} // namespace

extern "C" void kernel_launch(void* const* d_in, const int* in_sizes, int n_in,
                              void* d_out, int out_size, void* d_ws, size_t ws_size,
                              hipStream_t stream) {
  const int* edge_src   = (const int*)d_in[0];
  const int* edge_dst   = (const int*)d_in[1];
  const int* edge_type  = (const int*)d_in[2];
  const int* h_index    = (const int*)d_in[3];
  const int* t_index    = (const int*)d_in[4];
  const int* r_index    = (const int*)d_in[5];
  const float* query_emb= (const float*)d_in[6];
  const float* Wr       = (const float*)d_in[7];
  const float* br       = (const float*)d_in[8];
  const float* Wl       = (const float*)d_in[9];
  const float* bl       = (const float*)d_in[10];
  const float* W1       = (const float*)d_in[11];
  const float* b1       = (const float*)d_in[12];
  const float* W2       = (const float*)d_in[13];
  const float* b2       = (const float*)d_in[14];
  float* outp = (float*)d_out;
  (void)in_sizes; (void)n_in; (void)out_size; (void)ws_size;

  char* w = (char*)d_ws;
  auto alloc = [&](size_t bytes) {
    char* p = w;
    w += (bytes + 511) & ~(size_t)511;
    return p;
  };
  float* x0      = (float*)alloc(sizeof(float) * N * BD);
  float* x1      = (float*)alloc(sizeof(float) * N * BD);
  float* rel     = (float*)alloc(sizeof(float) * L * B * R2 * D);
  float* WT      = (float*)alloc(sizeof(float) * L * 13312);
  float* query   = (float*)alloc(sizeof(float) * BD);
  float* scales  = (float*)alloc(sizeof(float) * N * 3);
  float* meanacc = (float*)alloc(sizeof(float) * 16);
  int* row_start = (int*)alloc(sizeof(int) * (N + 1));
  int* cnt       = (int*)alloc(sizeof(int) * N);
  int* fill      = (int*)alloc(sizeof(int) * N);
  int* packed    = (int*)alloc(sizeof(int) * E);

  k_init<<<2048, 256, 0, stream>>>(x0, cnt, fill, meanacc);
  k_query<<<1, 256, 0, stream>>>(r_index, h_index, query_emb, query, x0);
  k_count<<<(E + 255) / 256, 256, 0, stream>>>(edge_dst, cnt);
  k_scan<<<1, 256, 0, stream>>>(cnt, row_start);
  k_scatter<<<(E + 255) / 256, 256, 0, stream>>>(edge_src, edge_dst, edge_type,
                                                 row_start, fill, packed);
  k_logsum<<<(N + 255) / 256, 256, 0, stream>>>(cnt, meanacc);
  k_scales<<<(N + 255) / 256, 256, 0, stream>>>(cnt, meanacc, scales);
  k_rel<<<(L * B * R2 * D + 255) / 256, 256, 0, stream>>>(query, Wr, br, rel);
  k_wt<<<(L * 13312 + 255) / 256, 256, 0, stream>>>(Wl, WT);

  const float* xin = x0;
  float* xout = x1;
  for (int l = 0; l < L; ++l) {
    k_layer<<<N / NPB, 512, 0, stream>>>(xin, xout,
        rel + (size_t)l * B * R2 * D, WT + (size_t)l * 13312, bl + l * D,
        scales, row_start, packed, h_index, query);
    const float* t = xout;
    xout = (float*)xin;
    xin = t;
  }
  // L is even -> final activations are back in x0 (== xin after last swap)
  k_score<<<B * NEG, 64, 0, stream>>>(xin, query, t_index, W1, b1, W2, b2, outp);
}